// Round 4
// baseline (217.755 us; speedup 1.0000x reference)
//
#include <hip/hip_runtime.h>

// Scatter-permute: out[expert_offsets[expert_idx[t]] + slot_idx[t], :] = token_hidden[t, :]
// T=65536 tokens, D=2048 f32 (8 KB/row). rows form a bijection over [0,T).
//
// Memory-bound: 1.074 GB total traffic; seq-copy ceiling ~6.3 TB/s -> ~171 us.
// R1 (block/row, seq-read + scat-write):   206 us = 5.2 TB/s
// R2 (grid-stride + nontemporal):          212 us
// R3 (wave/row, 8-deep ILP):               216 us
//   -> insensitive to issue shape; cost is the scattered WRITE address stream.
// R4: invert the permutation (cheap 256 KB index scatter), then gather:
//     scattered 8 KB READS + perfectly sequential writes. Tests whether the
//     memory system prefers scattered reads over scattered writes.

typedef float f32x4 __attribute__((ext_vector_type(4)));

__global__ void __launch_bounds__(256)
build_inverse_kernel(const int* __restrict__ expert_idx,
                     const int* __restrict__ slot_idx,
                     const int* __restrict__ expert_offsets,
                     int* __restrict__ inv, int T)
{
    const int t = blockIdx.x * 256 + threadIdx.x;
    if (t < T) {
        const int row = expert_offsets[expert_idx[t]] + slot_idx[t];
        inv[row] = t;   // bijection: every entry of inv is written
    }
}

__global__ void __launch_bounds__(256)
gather_rows_kernel(const f32x4* __restrict__ src,
                   const int* __restrict__ inv,
                   f32x4* __restrict__ dst)
{
    const int r = blockIdx.x;            // destination row (sequential writes)
    const int srow = inv[r];             // wave-uniform -> scalar load
    const f32x4* s = src + (size_t)srow * 512;
    f32x4*       d = dst + (size_t)r    * 512;

    // 512 f32x4 per row, 256 threads -> 2 coalesced vectors per lane.
    d[threadIdx.x]       = s[threadIdx.x];
    d[threadIdx.x + 256] = s[threadIdx.x + 256];
}

// Fallback (R1 form) if d_ws is too small for the inverse index.
__global__ void __launch_bounds__(256)
scatter_rows_kernel(const f32x4* __restrict__ src,
                    const int* __restrict__ expert_idx,
                    const int* __restrict__ slot_idx,
                    const int* __restrict__ expert_offsets,
                    f32x4* __restrict__ dst)
{
    const int t = blockIdx.x;
    const int row = expert_offsets[expert_idx[t]] + slot_idx[t];
    const f32x4* s = src + (size_t)t   * 512;
    f32x4*       d = dst + (size_t)row * 512;
    d[threadIdx.x]       = s[threadIdx.x];
    d[threadIdx.x + 256] = s[threadIdx.x + 256];
}

extern "C" void kernel_launch(void* const* d_in, const int* in_sizes, int n_in,
                              void* d_out, int out_size, void* d_ws, size_t ws_size,
                              hipStream_t stream) {
    const float* token_hidden   = (const float*)d_in[0];
    const int*   expert_idx     = (const int*)  d_in[1];
    const int*   slot_idx       = (const int*)  d_in[2];
    const int*   expert_offsets = (const int*)  d_in[3];

    const int T = in_sizes[1];            // 65536 tokens (rows)

    if (ws_size >= (size_t)T * sizeof(int)) {
        int* inv = (int*)d_ws;
        build_inverse_kernel<<<(T + 255) / 256, 256, 0, stream>>>(
            expert_idx, slot_idx, expert_offsets, inv, T);
        gather_rows_kernel<<<T, 256, 0, stream>>>(
            (const f32x4*)token_hidden, inv, (f32x4*)d_out);
    } else {
        scatter_rows_kernel<<<T, 256, 0, stream>>>(
            (const f32x4*)token_hidden, expert_idx, slot_idx, expert_offsets,
            (f32x4*)d_out);
    }
}

// Round 5
// 208.620 us; speedup vs baseline: 1.0438x; 1.0438x over previous
//
#include <hip/hip_runtime.h>

// Scatter-permute: out[expert_offsets[expert_idx[t]] + slot_idx[t], :] = token_hidden[t, :]
// T=65536 tokens, D=2048 f32 (8 KB/row). rows form a bijection over [0,T) ->
// every output row is written exactly once, so no zero-init of d_out is needed.
//
// Memory-bound: 1.074 GB total traffic; seq-copy ceiling ~6.3 TB/s -> ~171 us.
// R1 (block/row, seq-read + scat-write):        206 us = 5.2 TB/s   <- best
// R2 (grid-stride + NT load AND store):         212 us  (2 vars at once)
// R3 (wave/row, 8-deep ILP):                    216 us
// R4 (inverse perm: scat-read + seq-write):     218 us
//   -> insensitive to scatter direction and issue shape.
// R5: clean single-variable ablation of R2 -- R1 structure exactly, but
//     NONTEMPORAL STORES only (temporal loads). Write stream is single-use;
//     NT store avoids L2 write-allocate churn against the read stream.

typedef float f32x4 __attribute__((ext_vector_type(4)));

__global__ void __launch_bounds__(256)
scatter_rows_kernel(const f32x4* __restrict__ src,
                    const int* __restrict__ expert_idx,
                    const int* __restrict__ slot_idx,
                    const int* __restrict__ expert_offsets,
                    f32x4* __restrict__ dst)
{
    const int t = blockIdx.x;
    // Wave-uniform index loads -> scalar path.
    const int row = expert_offsets[expert_idx[t]] + slot_idx[t];

    const f32x4* s = src + (size_t)t   * 512;
    f32x4*       d = dst + (size_t)row * 512;

    // 512 f32x4 per row, 256 threads -> 2 coalesced vectors per lane.
    f32x4 a = s[threadIdx.x];
    f32x4 b = s[threadIdx.x + 256];
    __builtin_nontemporal_store(a, &d[threadIdx.x]);
    __builtin_nontemporal_store(b, &d[threadIdx.x + 256]);
}

extern "C" void kernel_launch(void* const* d_in, const int* in_sizes, int n_in,
                              void* d_out, int out_size, void* d_ws, size_t ws_size,
                              hipStream_t stream) {
    const float* token_hidden   = (const float*)d_in[0];
    const int*   expert_idx     = (const int*)  d_in[1];
    const int*   slot_idx       = (const int*)  d_in[2];
    const int*   expert_offsets = (const int*)  d_in[3];

    const int T = in_sizes[1];            // 65536 tokens (rows)

    scatter_rows_kernel<<<T, 256, 0, stream>>>(
        (const f32x4*)token_hidden, expert_idx, slot_idx, expert_offsets,
        (f32x4*)d_out);
}